// Round 3
// baseline (35.593 us; speedup 1.0000x reference)
//
#include <hip/hip_runtime.h>
#include <math.h>

// Chamfer loss, B=8, N=M=4096, D=3, fp32.
// k1: pairwise min over target chunks (2 dirs fused), 3.5 VALU ops/pair
//     (|x|^2 deferred; paired targets folded with v_min3_f32).
// k2: min-over-16-chunks + weighted block sums + last-block final reduce.

constexpr int BATCH = 8;
constexpr int NP    = 4096;   // points per cloud
constexpr int MC    = 16;     // target chunks
constexpr int MCH   = 256;    // target points per chunk
constexpr int KPT   = 8;      // query points per thread
constexpr int T     = 256;    // threads per block

// ws layout in floats:
//   [0,            524288)  pmin dir0 (queries = x): [b][mc][n]
//   [524288,      1048576)  pmin dir1 (queries = y)
//   [1048576,     1048832)  256 per-block weighted partial sums
//   [1048832]               done-counter (uint), reset by k1 each call
constexpr size_t PMIN_STRIDE = (size_t)BATCH * MC * NP; // 524288
constexpr size_t PS_OFF      = 2 * PMIN_STRIDE;         // 1048576
constexpr int    PS_N        = 256;
constexpr size_t CTR_OFF     = PS_OFF + PS_N;

__global__ __launch_bounds__(T) void chamfer_partial(
    const float* __restrict__ x, const float* __restrict__ y,
    float* __restrict__ ws)
{
    const int bid = blockIdx.x;          // 512 blocks
    if (bid == 0 && threadIdx.x == 0) {
        // deterministic per-call reset of the done-counter used by k2
        *reinterpret_cast<unsigned int*>(ws + CTR_OFF) = 0u;
    }
    const int dir = bid >> 8;            // 0: query=x target=y ; 1: swapped
    const int r   = bid & 255;
    const int b   = r >> 5;              // batch
    const int xc  = (r >> 4) & 1;        // query chunk (2048 queries each)
    const int mc  = r & 15;              // target chunk (256 targets each)

    const float* q = dir ? y : x;
    const float* t = dir ? x : y;

    __shared__ float4 ty[MCH];           // (t0, t1, t2, |t|^2)  4 KB
    const int tid = threadIdx.x;

    const float* tb = t + (size_t)(b * NP + mc * MCH) * 3;
    {   // T == MCH: one target per thread
        float t0 = tb[3 * tid + 0];
        float t1 = tb[3 * tid + 1];
        float t2 = tb[3 * tid + 2];
        ty[tid] = make_float4(t0, t1, t2, fmaf(t0, t0, fmaf(t1, t1, t2 * t2)));
    }

    // Load 8 query points (24 consecutive floats, 16B-aligned) as 6x float4.
    const int n0 = b * NP + xc * 2048 + tid * KPT;
    const float4* qb = reinterpret_cast<const float4*>(q + (size_t)n0 * 3);
    float4 v0 = qb[0], v1 = qb[1], v2 = qb[2], v3 = qb[3], v4 = qb[4], v5 = qb[5];
    float px[KPT][3] = {
        {v0.x, v0.y, v0.z}, {v0.w, v1.x, v1.y},
        {v1.z, v1.w, v2.x}, {v2.y, v2.z, v2.w},
        {v3.x, v3.y, v3.z}, {v3.w, v4.x, v4.y},
        {v4.z, v4.w, v5.x}, {v5.y, v5.z, v5.w},
    };
    float xn[KPT][3], x2s[KPT], mn[KPT];
    #pragma unroll
    for (int k = 0; k < KPT; ++k) {
        x2s[k] = fmaf(px[k][0], px[k][0], fmaf(px[k][1], px[k][1], px[k][2] * px[k][2]));
        #pragma unroll
        for (int d = 0; d < 3; ++d) xn[k][d] = -2.0f * px[k][d];
        mn[k] = INFINITY;
    }

    __syncthreads();

    // min over j of d' = |t|^2 - 2 q.t   (|q|^2 added in epilogue)
    // paired: mn = min3(mn, d_a, d_b) -> 7 VALU per 2 targets per query
    #pragma unroll 4
    for (int j = 0; j < MCH; j += 2) {
        float4 ta = ty[j];               // wave-uniform -> LDS broadcast
        float4 tc = ty[j + 1];
        #pragma unroll
        for (int k = 0; k < KPT; ++k) {
            float da = fmaf(xn[k][2], ta.z, ta.w);
            da = fmaf(xn[k][1], ta.y, da);
            da = fmaf(xn[k][0], ta.x, da);
            float db = fmaf(xn[k][2], tc.z, tc.w);
            db = fmaf(xn[k][1], tc.y, db);
            db = fmaf(xn[k][0], tc.x, db);
            float m;
            asm("v_min3_f32 %0, %1, %2, %3"
                : "=v"(m) : "v"(mn[k]), "v"(da), "v"(db));
            mn[k] = m;
        }
    }

    float4 o0, o1;
    o0.x = fmaxf(x2s[0] + mn[0], 0.0f);
    o0.y = fmaxf(x2s[1] + mn[1], 0.0f);
    o0.z = fmaxf(x2s[2] + mn[2], 0.0f);
    o0.w = fmaxf(x2s[3] + mn[3], 0.0f);
    o1.x = fmaxf(x2s[4] + mn[4], 0.0f);
    o1.y = fmaxf(x2s[5] + mn[5], 0.0f);
    o1.z = fmaxf(x2s[6] + mn[6], 0.0f);
    o1.w = fmaxf(x2s[7] + mn[7], 0.0f);

    float* pm = ws + (size_t)dir * PMIN_STRIDE
                   + ((size_t)(b * MC + mc)) * NP
                   + (size_t)xc * 2048 + (size_t)tid * KPT;
    reinterpret_cast<float4*>(pm)[0] = o0;
    reinterpret_cast<float4*>(pm)[1] = o1;
}

__global__ __launch_bounds__(T) void chamfer_combine(
    float* __restrict__ ws, const float* __restrict__ w,
    float* __restrict__ out)
{
    const int bid = blockIdx.x;          // 256 blocks: dir(2) x b(8) x nq(16)
    const int dir = bid >> 7;
    const int b   = (bid >> 4) & 7;
    const int nq  = bid & 15;
    const int tid = threadIdx.x;

    const float* base = ws + (size_t)dir * PMIN_STRIDE + (size_t)b * MC * NP;
    float* ps = ws + PS_OFF;
    unsigned int* ctr = reinterpret_cast<unsigned int*>(ws + CTR_OFF);

    // min over the 16 target chunks for this thread's query
    const int n = nq * 256 + tid;
    float v = INFINITY;
    #pragma unroll
    for (int m = 0; m < MC; ++m) v = fminf(v, base[(size_t)m * NP + n]);

    // fixed-order block reduction of v
    float sum = v;
    for (int off = 32; off; off >>= 1) sum += __shfl_down(sum, off, 64);
    __shared__ float red[4];
    __shared__ int lastflag;
    if ((tid & 63) == 0) red[tid >> 6] = sum;
    __syncthreads();

    if (tid == 0) {
        float bs = (red[0] + red[1]) + (red[2] + red[3]);
        bs *= w[b] * (1.0f / ((float)NP * (float)BATCH));
        __hip_atomic_store(&ps[bid], bs, __ATOMIC_RELEASE,
                           __HIP_MEMORY_SCOPE_AGENT);
        __threadfence();
        unsigned int old = atomicAdd(ctr, 1u);   // device scope
        lastflag = (old == 255u) ? 1 : 0;
    }
    __syncthreads();

    if (lastflag) {
        __threadfence();                 // acquire side
        float p = __hip_atomic_load(&ps[tid], __ATOMIC_ACQUIRE,
                                    __HIP_MEMORY_SCOPE_AGENT);
        float acc = p;
        for (int off = 32; off; off >>= 1) acc += __shfl_down(acc, off, 64);
        if ((tid & 63) == 0) red[tid >> 6] = acc;
        __syncthreads();
        if (tid == 0) out[0] = (red[0] + red[1]) + (red[2] + red[3]);
    }
}

extern "C" void kernel_launch(void* const* d_in, const int* in_sizes, int n_in,
                              void* d_out, int out_size, void* d_ws, size_t ws_size,
                              hipStream_t stream) {
    const float* x = (const float*)d_in[0];   // (8, 4096, 3)
    const float* y = (const float*)d_in[1];   // (8, 4096, 3)
    const float* w = (const float*)d_in[2];   // (8,)
    float* out = (float*)d_out;
    float* ws  = (float*)d_ws;

    chamfer_partial<<<512, T, 0, stream>>>(x, y, ws);
    chamfer_combine<<<256, T, 0, stream>>>(ws, w, out);
}